// Round 20
// baseline (198.101 us; speedup 1.0000x reference)
//
#include <hip/hip_runtime.h>
#include <math.h>
#include <float.h>
#include <stdint.h>

// NearestNeighborRatio: desc1/desc2 (B=16384, D=128) f32.
// d2(i,j) = |a_i|^2 + |b_j|^2 - 2 a_i.b_j; per-row top-2, ratio = sqrt(d0/d1), mask = ratio<=0.8.
// f16 hi/lo split (x = hi + lo): dot via 3 MFMAs (hh + hl + lh) in fp32 acc.
// v20: v18 (3-slot rotation + counted vmcnt) with B traffic SPLIT across pipes:
//      lo-plane kk=2,3 fragments (25% of B bytes) load direct global->reg (L2 path),
//      rest stays LDS. LDS window 1542->1157 cyc (was the binding pipe at exactly the
//      measured 60% MfmaUtil); ceiling -> 80%. Slots 12KB, stage 3 chunks/wave.
//      Convert kernel fused with norms (v19).
// Out (flat f32): [0,B) match_dists ; [B,3B) matches_idxs as floats ; [3B,4B) mask 0/1.

typedef __attribute__((ext_vector_type(4))) float     f32x4;
typedef __attribute__((ext_vector_type(8))) _Float16  half8;

#define D_     128
#define BM_    256   // rows per block (4 waves x 64)
#define BN_    32    // cols per tile
#define CS_    8     // column splits
#define PARTS_ 8     // partials per row = CS_
// LDS map: slots 0/12288/24576 (12KB each: hi 8KB + lo-kk01 4KB); sq_lds 36864 -> 45056

__device__ __forceinline__ void gload_lds16(const void* g, void* l) {
  auto gp = (const __attribute__((address_space(1))) unsigned int*)(uintptr_t)g;
  auto lp = (__attribute__((address_space(3))) unsigned int*)(uintptr_t)l;
  __builtin_amdgcn_global_load_lds(gp, lp, 16, 0, 0);
}

// A planes: row-major [B][128] f16 (unscaled).
// B planes: packed fragment order per 32-col tile, PRE-SCALED BY -2:
//   f16 offset = t*4096 + kk*1024 + nf*512 + g*128 + c15*8
//   holds -2*desc2[t*32 + nf*16 + c15][kk*32 + g*8 .. +8]
// Also computes row norms: sq[desc] (desc1) / sq[B+desc] (desc2), 16-lane shfl reduce.
__global__ void convert_kernel(const float* __restrict__ d1, const float* __restrict__ d2,
                               _Float16* __restrict__ Ahi, _Float16* __restrict__ Alo,
                               _Float16* __restrict__ BhiP, _Float16* __restrict__ BloP,
                               float* __restrict__ sq, int B) {
  int i = blockIdx.x * blockDim.x + threadIdx.x;
  int total = B * 16;                       // 8-elem groups per matrix
  if (i >= 2 * total) return;
  bool isB = i >= total;
  int j    = isB ? i - total : i;
  int desc = j >> 4;
  int seg  = j & 15;                        // 8-f32 group within the row
  const float* src = (isB ? d2 : d1) + (size_t)desc * D_ + seg * 8;
  float4 v0 = *(const float4*)(src);
  float4 v1 = *(const float4*)(src + 4);
  half8 hv, lv;
  float e[8] = {v0.x, v0.y, v0.z, v0.w, v1.x, v1.y, v1.z, v1.w};
  float ss = 0.f;
  #pragma unroll
  for (int q = 0; q < 8; ++q) {
    ss = fmaf(e[q], e[q], ss);
    _Float16 h = (_Float16)e[q];
    _Float16 l = (_Float16)(e[q] - (float)h);
    if (isB) { h = (_Float16)(-2.0f) * h; l = (_Float16)(-2.0f) * l; }
    hv[q] = h; lv[q] = l;
  }
  #pragma unroll
  for (int off = 8; off > 0; off >>= 1) ss += __shfl_xor(ss, off, 64);
  if (seg == 0) sq[(isB ? B : 0) + desc] = ss;

  if (!isB) {
    *(half8*)(Ahi + (size_t)desc * D_ + seg * 8) = hv;
    *(half8*)(Alo + (size_t)desc * D_ + seg * 8) = lv;
  } else {
    int t   = desc >> 5, cloc = desc & 31;
    int nf  = cloc >> 4, c15  = cloc & 15;
    int kk  = seg >> 2,  gq   = seg & 3;
    size_t off = (size_t)t * 4096 + kk * 1024 + nf * 512 + gq * 128 + c15 * 8;
    *(half8*)(BhiP + off) = hv;
    *(half8*)(BloP + off) = lv;
  }
}

__global__ __launch_bounds__(256, 2)
void nn_mfma(const _Float16* __restrict__ Ahi, const _Float16* __restrict__ Alo,
             const _Float16* __restrict__ BhiP, const _Float16* __restrict__ BloP,
             const float* __restrict__ sqb,
             float* __restrict__ p_d0, float* __restrict__ p_d1,
             int* __restrict__ p_j0, int B) {
  extern __shared__ char smem[];
  float* sq_lds = (float*)(smem + 36864);
  const int tid  = threadIdx.x;
  const int lane = tid & 63;
  const int wid  = tid >> 6;       // wave row-group: rows wid*64..wid*64+63
  const int l15  = lane & 15;
  const int g    = lane >> 4;

  const int nrb   = B / BM_;            // 64
  const int rb    = blockIdx.x % nrb;
  const int cspl  = blockIdx.x / nrb;
  const int i0    = rb * BM_;
  const int niter = (B / CS_) / BN_;    // 64
  const int tile0 = cspl * niter;

  // ---- A fragments -> registers, once (64 rows per wave: mf=0..3) ----
  half8 ah[4][4], al[4][4];
  #pragma unroll
  for (int mf = 0; mf < 4; ++mf) {
    int row = i0 + wid * 64 + mf * 16 + l15;
    const _Float16* pa = Ahi + (size_t)row * D_ + g * 8;
    const _Float16* pl = Alo + (size_t)row * D_ + g * 8;
    #pragma unroll
    for (int kk = 0; kk < 4; ++kk) {
      ah[mf][kk] = *(const half8*)(pa + kk * 32);
      al[mf][kk] = *(const half8*)(pl + kk * 32);
    }
  }

  // ---- sq strip -> LDS once (2048 f32 = 8KB) ----
  {
    const float* sqs = sqb + cspl * 2048;
    #pragma unroll
    for (int e = 0; e < 2; ++e) {
      int idx = tid + e * 256;
      float4 v = ((const float4*)sqs)[idx];
      ((float4*)sq_lds)[idx] = v;
    }
  }

  // ---- staging: 12 x 1KB chunks per tile (hi 8 + lo-kk01 4); wave stages 3 ----
  //   chunk c<8: hi plane bytes c*1024; c>=8: lo plane bytes (c-8)*1024.
  auto stage = [&](int slotbase, int t) {
    const size_t tb = (size_t)(tile0 + t) * 4096;   // f16 elements
    #pragma unroll
    for (int e = 0; e < 3; ++e) {
      int c = wid * 3 + e;
      const _Float16* s = (c < 8) ? (BhiP + tb + c * 512 + lane * 8)
                                  : (BloP + tb + (c - 8) * 512 + lane * 8);
      gload_lds16(s, smem + slotbase + c * 1024);
    }
  };

  float best0[16], best1[16]; int bj[16];
  #pragma unroll
  for (int s = 0; s < 16; ++s) { best0[s] = FLT_MAX; best1[s] = FLT_MAX; bj[s] = 0x7fffffff; }

  const int colg0 = tile0 * BN_ + l15;

  // ---- prologue: stage tiles 0,1 into slots 0,1 (3 loads each per wave) ----
  stage(0, 0);
  stage(12288, 1);
  asm volatile("s_waitcnt vmcnt(3)" ::: "memory");     // tile 0 landed; tile 1 in flight
  asm volatile("s_waitcnt lgkmcnt(0)" ::: "memory");   // sq_lds visible
  __builtin_amdgcn_s_barrier();
  asm volatile("" ::: "memory");

  int bcur = 0, bstage = 24576;
  for (int it = 0; it < niter; ++it) {
    // direct global->reg: lo-plane fragments for kk=2,3 (consumed after kk=0,1 MFMAs)
    const _Float16* blsrc = BloP + (size_t)(tile0 + it) * 4096 + lane * 8;
    half8 blr[2][2];
    #pragma unroll
    for (int dk = 0; dk < 2; ++dk)
      #pragma unroll
      for (int nf = 0; nf < 2; ++nf)
        blr[dk][nf] = *(const half8*)(blsrc + (2 + dk) * 1024 + nf * 512);

    // stage tile t+2 into rotation slot
    if (it + 2 < niter) stage(bstage, it + 2);

    float sjc0 = sq_lds[it * 32 + l15];
    float sjc1 = sq_lds[it * 32 + 16 + l15];

    f32x4 acc[4][2];
    __builtin_amdgcn_s_setprio(1);
    #pragma unroll
    for (int kk = 0; kk < 4; ++kk) {
      half8 bh[2], bl[2];
      #pragma unroll
      for (int nf = 0; nf < 2; ++nf) {
        bh[nf] = *(const half8*)(smem + bcur + (kk * 2 + nf) * 1024 + lane * 16);
        if (kk < 2)
          bl[nf] = *(const half8*)(smem + bcur + 8192 + (kk * 2 + nf) * 1024 + lane * 16);
        else
          bl[nf] = blr[kk - 2][nf];
      }
      // term hh (C-init with sj at kk==0)
      #pragma unroll
      for (int mf = 0; mf < 4; ++mf)
        #pragma unroll
        for (int nf = 0; nf < 2; ++nf) {
          if (kk == 0) {
            float sj = nf ? sjc1 : sjc0;
            f32x4 c0 = {sj, sj, sj, sj};
            acc[mf][nf] = __builtin_amdgcn_mfma_f32_16x16x32_f16(ah[mf][0], bh[nf], c0, 0, 0, 0);
          } else {
            acc[mf][nf] = __builtin_amdgcn_mfma_f32_16x16x32_f16(ah[mf][kk], bh[nf], acc[mf][nf], 0, 0, 0);
          }
        }
      // term hl
      #pragma unroll
      for (int mf = 0; mf < 4; ++mf)
        #pragma unroll
        for (int nf = 0; nf < 2; ++nf)
          acc[mf][nf] = __builtin_amdgcn_mfma_f32_16x16x32_f16(ah[mf][kk], bl[nf], acc[mf][nf], 0, 0, 0);
      // term lh
      #pragma unroll
      for (int mf = 0; mf < 4; ++mf)
        #pragma unroll
        for (int nf = 0; nf < 2; ++nf)
          acc[mf][nf] = __builtin_amdgcn_mfma_f32_16x16x32_f16(al[mf][kk], bh[nf], acc[mf][nf], 0, 0, 0);
    }
    __builtin_amdgcn_s_setprio(0);

    // ---- top-2 fold (fmed3, 4 VALU/elem); acc = sqb[j] - 2*dot already ----
    // C/D layout: col = lane&15, row = (lane>>4)*4 + reg
    #pragma unroll
    for (int nf = 0; nf < 2; ++nf) {
      int colg = colg0 + it * BN_ + nf * 16;
      #pragma unroll
      for (int mf = 0; mf < 4; ++mf)
        #pragma unroll
        for (int r = 0; r < 4; ++r) {
          int s = mf * 4 + r;
          float t = acc[mf][nf][r];
          best1[s] = __builtin_amdgcn_fmed3f(t, best0[s], best1[s]);
          bool lt0 = t < best0[s];
          best0[s] = fminf(t, best0[s]);
          bj[s]    = lt0 ? colg : bj[s];
        }
    }

    // ---- counted drain: stage(t+1) already retired by the blr-use wait (older in
    //      FIFO); leave stage(t+2)'s 3 loads in flight across the barrier ----
    if (it + 2 < niter) asm volatile("s_waitcnt vmcnt(3)" ::: "memory");
    else                asm volatile("s_waitcnt vmcnt(0)" ::: "memory");
    __builtin_amdgcn_s_barrier();
    asm volatile("" ::: "memory");

    bcur   = (bcur   == 24576) ? 0 : bcur   + 12288;
    bstage = (bstage == 24576) ? 0 : bstage + 12288;
  }

  // ---- merge across the 16 col-lanes (same g), index tie-break ----
  #pragma unroll
  for (int off = 1; off < 16; off <<= 1) {
    #pragma unroll
    for (int s = 0; s < 16; ++s) {
      float e0 = __shfl_xor(best0[s], off, 64);
      float e1 = __shfl_xor(best1[s], off, 64);
      int   f0 = __shfl_xor(bj[s],    off, 64);
      if (e0 < best0[s] || (e0 == best0[s] && f0 < bj[s])) {
        best1[s] = fminf(best0[s], e1);
        best0[s] = e0;
        bj[s]    = f0;
      } else {
        best1[s] = fminf(best1[s], e0);
      }
    }
  }

  if (l15 == 0) {
    #pragma unroll
    for (int s = 0; s < 16; ++s) {
      int mf = s >> 2, r = s & 3;
      int row = i0 + wid * 64 + mf * 16 + g * 4 + r;
      p_d0[row * PARTS_ + cspl] = best0[s];
      p_d1[row * PARTS_ + cspl] = best1[s];
      p_j0[row * PARTS_ + cspl] = bj[s];
    }
  }
}

__global__ void nn_final(const float* __restrict__ sqa,
                         const float* __restrict__ p_d0,
                         const float* __restrict__ p_d1,
                         const int* __restrict__ p_j0,
                         float* __restrict__ out, int B) {
  int row = blockIdx.x * blockDim.x + threadIdx.x;
  if (row >= B) return;
  float d0 = FLT_MAX, d1 = FLT_MAX;
  int j0 = 0x7fffffff;
  for (int cs = 0; cs < PARTS_; ++cs) {
    float e0 = p_d0[row * PARTS_ + cs];
    float e1 = p_d1[row * PARTS_ + cs];
    int   f0 = p_j0[row * PARTS_ + cs];
    if (e0 < d0 || (e0 == d0 && f0 < j0)) {
      d1 = fminf(d0, e1);
      d0 = e0;
      j0 = f0;
    } else {
      d1 = fminf(d1, e0);
    }
  }
  float sa = sqa[row];
  float v0 = sqrtf(fmaxf(sa + d0, 0.f));
  float v1 = sqrtf(fmaxf(sa + d1, 0.f));
  float ratio = v0 / v1;
  bool m = (ratio <= 0.8f);
  out[row]             = m ? ratio : 0.f;
  out[B + row * 2]     = (float)row;
  out[B + row * 2 + 1] = (float)j0;
  out[3 * B + row]     = m ? 1.f : 0.f;
}

extern "C" void kernel_launch(void* const* d_in, const int* in_sizes, int n_in,
                              void* d_out, int out_size, void* d_ws, size_t ws_size,
                              hipStream_t stream) {
  const float* d1 = (const float*)d_in[0];
  const float* d2 = (const float*)d_in[1];
  const int B = in_sizes[0] / D_;    // 16384

  float* ws   = (float*)d_ws;
  float* sqa  = ws;                       // [0, B)
  float* sqb  = ws + B;                   // [B, 2B)
  float* p_d0 = ws + 2 * B;               // [2B, 10B)
  float* p_d1 = ws + 10 * B;              // [10B, 18B)
  int*   p_j0 = (int*)(ws + 18 * B);      // [18B, 26B)
  _Float16* Ahi  = (_Float16*)(ws + 26 * B);
  _Float16* Alo  = Ahi + (size_t)B * D_;
  _Float16* BhiP = Alo + (size_t)B * D_;
  _Float16* BloP = BhiP + (size_t)B * D_;

  // fused convert + norms
  int ngroups = 2 * B * 16;
  convert_kernel<<<(ngroups + 255) / 256, 256, 0, stream>>>(d1, d2, Ahi, Alo, BhiP, BloP, sqa, B);

  // main MFMA kernel: 44 KiB dynamic LDS (3 x 12KB slots + sq strip), 2 blocks/CU
  hipFuncSetAttribute((const void*)nn_mfma,
                      hipFuncAttributeMaxDynamicSharedMemorySize, 45056);
  nn_mfma<<<(B / BM_) * CS_, 256, 45056, stream>>>(Ahi, Alo, BhiP, BloP, sqb,
                                                   p_d0, p_d1, p_j0, B);

  // final merge + outputs
  nn_final<<<(B + 255) / 256, 256, 0, stream>>>(sqa, p_d0, p_d1, p_j0, (float*)d_out, B);
}

// Round 21
// 171.492 us; speedup vs baseline: 1.1552x; 1.1552x over previous
//
#include <hip/hip_runtime.h>
#include <math.h>
#include <float.h>
#include <stdint.h>

// NearestNeighborRatio: desc1/desc2 (B=16384, D=128) f32.
// d2(i,j) = |a_i|^2 + |b_j|^2 - 2 a_i.b_j; per-row top-2, ratio = sqrt(d0/d1), mask = ratio<=0.8.
// f16 hi/lo split (x = hi + lo): dot via 3 MFMAs (hh + hl + lh) in fp32 acc.
// v21 = best-known components: R18 main kernel (3-slot LDS rotation + counted vmcnt(4),
//      never draining the staging FIFO in-loop; sq strip in LDS) + R19's convert kernel
//      with norms fused (one less 16MB-read pass). Kernel sits at its measured LDS
//      roofline: 128KB B-frag reads per 2-tile window @ ~85 B/cyc = 1542 cyc vs 932 cyc
//      MFMA -> 60% MfmaUtil ceiling == measured.
// Out (flat f32): [0,B) match_dists ; [B,3B) matches_idxs as floats ; [3B,4B) mask 0/1.

typedef __attribute__((ext_vector_type(4))) float     f32x4;
typedef __attribute__((ext_vector_type(8))) _Float16  half8;

#define D_     128
#define BM_    256   // rows per block (4 waves x 64)
#define BN_    32    // cols per tile
#define CS_    8     // column splits
#define PARTS_ 8     // partials per row = CS_
// LDS map: buf0 0, buf1 16384, buf2 32768, sq_lds 49152 (2048 f32) -> 57344 total

__device__ __forceinline__ void gload_lds16(const void* g, void* l) {
  auto gp = (const __attribute__((address_space(1))) unsigned int*)(uintptr_t)g;
  auto lp = (__attribute__((address_space(3))) unsigned int*)(uintptr_t)l;
  __builtin_amdgcn_global_load_lds(gp, lp, 16, 0, 0);
}

// A planes: row-major [B][128] f16 (unscaled).
// B planes: packed fragment order per 32-col tile, PRE-SCALED BY -2:
//   f16 offset = t*4096 + kk*1024 + nf*512 + g*128 + c15*8
//   holds -2*desc2[t*32 + nf*16 + c15][kk*32 + g*8 .. +8]
// Also computes row norms: sq[desc] (desc1) / sq[B+desc] (desc2), 16-lane shfl reduce.
__global__ void convert_kernel(const float* __restrict__ d1, const float* __restrict__ d2,
                               _Float16* __restrict__ Ahi, _Float16* __restrict__ Alo,
                               _Float16* __restrict__ BhiP, _Float16* __restrict__ BloP,
                               float* __restrict__ sq, int B) {
  int i = blockIdx.x * blockDim.x + threadIdx.x;
  int total = B * 16;                       // 8-elem groups per matrix
  if (i >= 2 * total) return;
  bool isB = i >= total;
  int j    = isB ? i - total : i;
  int desc = j >> 4;
  int seg  = j & 15;                        // 8-f32 group within the row
  const float* src = (isB ? d2 : d1) + (size_t)desc * D_ + seg * 8;
  float4 v0 = *(const float4*)(src);
  float4 v1 = *(const float4*)(src + 4);
  half8 hv, lv;
  float e[8] = {v0.x, v0.y, v0.z, v0.w, v1.x, v1.y, v1.z, v1.w};
  float ss = 0.f;
  #pragma unroll
  for (int q = 0; q < 8; ++q) {
    ss = fmaf(e[q], e[q], ss);
    _Float16 h = (_Float16)e[q];
    _Float16 l = (_Float16)(e[q] - (float)h);
    if (isB) { h = (_Float16)(-2.0f) * h; l = (_Float16)(-2.0f) * l; }
    hv[q] = h; lv[q] = l;
  }
  // 16-lane reduce (groups of 16 aligned within the wave)
  #pragma unroll
  for (int off = 8; off > 0; off >>= 1) ss += __shfl_xor(ss, off, 64);
  if (seg == 0) sq[(isB ? B : 0) + desc] = ss;

  if (!isB) {
    *(half8*)(Ahi + (size_t)desc * D_ + seg * 8) = hv;
    *(half8*)(Alo + (size_t)desc * D_ + seg * 8) = lv;
  } else {
    int t   = desc >> 5, cloc = desc & 31;
    int nf  = cloc >> 4, c15  = cloc & 15;
    int kk  = seg >> 2,  gq   = seg & 3;
    size_t off = (size_t)t * 4096 + kk * 1024 + nf * 512 + gq * 128 + c15 * 8;
    *(half8*)(BhiP + off) = hv;
    *(half8*)(BloP + off) = lv;
  }
}

__global__ __launch_bounds__(256, 2)
void nn_mfma(const _Float16* __restrict__ Ahi, const _Float16* __restrict__ Alo,
             const _Float16* __restrict__ BhiP, const _Float16* __restrict__ BloP,
             const float* __restrict__ sqb,
             float* __restrict__ p_d0, float* __restrict__ p_d1,
             int* __restrict__ p_j0, int B) {
  extern __shared__ char smem[];
  float* sq_lds = (float*)(smem + 49152);
  const int tid  = threadIdx.x;
  const int lane = tid & 63;
  const int wid  = tid >> 6;       // wave row-group: rows wid*64..wid*64+63
  const int l15  = lane & 15;
  const int g    = lane >> 4;

  const int nrb   = B / BM_;            // 64
  const int rb    = blockIdx.x % nrb;
  const int cspl  = blockIdx.x / nrb;
  const int i0    = rb * BM_;
  const int niter = (B / CS_) / BN_;    // 64
  const int tile0 = cspl * niter;

  // ---- A fragments -> registers, once (64 rows per wave: mf=0..3) ----
  half8 ah[4][4], al[4][4];
  #pragma unroll
  for (int mf = 0; mf < 4; ++mf) {
    int row = i0 + wid * 64 + mf * 16 + l15;
    const _Float16* pa = Ahi + (size_t)row * D_ + g * 8;
    const _Float16* pl = Alo + (size_t)row * D_ + g * 8;
    #pragma unroll
    for (int kk = 0; kk < 4; ++kk) {
      ah[mf][kk] = *(const half8*)(pa + kk * 32);
      al[mf][kk] = *(const half8*)(pl + kk * 32);
    }
  }

  // ---- sq strip -> LDS once (2048 f32 = 8KB) ----
  {
    const float* sqs = sqb + cspl * 2048;
    #pragma unroll
    for (int e = 0; e < 2; ++e) {
      int idx = tid + e * 256;                  // float4 index 0..511
      float4 v = ((const float4*)sqs)[idx];
      ((float4*)sq_lds)[idx] = v;
    }
  }

  // ---- staging: 16 x 1KB chunks per tile; wave wid stages 4 (one gload each) ----
  const _Float16* srcW = ((wid < 2) ? BhiP : BloP)
                       + (size_t)tile0 * 4096 + (wid & 1) * 2048 + lane * 8;
  char* ldsW = smem + (wid >> 1) * 8192 + (wid & 1) * 4096;   // + bufbase
  auto stage = [&](int bufbase, int it) {
    const _Float16* s = srcW + (size_t)it * 4096;
    char* l = ldsW + bufbase;
    #pragma unroll
    for (int e = 0; e < 4; ++e) gload_lds16(s + e * 512, l + e * 1024);
  };

  float best0[16], best1[16]; int bj[16];
  #pragma unroll
  for (int s = 0; s < 16; ++s) { best0[s] = FLT_MAX; best1[s] = FLT_MAX; bj[s] = 0x7fffffff; }

  const int colg0 = tile0 * BN_ + l15;

  // ---- prologue: stage tiles 0,1; drain tile0 (per-wave 4 newest stay in flight) ----
  stage(0, 0);
  stage(16384, 1);
  asm volatile("s_waitcnt vmcnt(4)" ::: "memory");
  asm volatile("s_waitcnt lgkmcnt(0)" ::: "memory");   // sq_lds writes visible
  __builtin_amdgcn_s_barrier();
  asm volatile("" ::: "memory");

  float sjc0 = sq_lds[l15];
  float sjc1 = sq_lds[16 + l15];

  int bcur = 0, bstage = 32768;
  for (int it = 0; it < niter; ++it) {
    // issue tile t+2 into the rotation buffer (its readers finished at t-1, barrier-ordered)
    if (it + 2 < niter) stage(bstage, it + 2);
    // prefetch next iter's sj from LDS (lgkm only — vmcnt FIFO stays pure stage loads)
    float sjn0 = 0.f, sjn1 = 0.f;
    if (it + 1 < niter) {
      sjn0 = sq_lds[(it + 1) * 32 + l15];
      sjn1 = sq_lds[(it + 1) * 32 + 16 + l15];
    }

    f32x4 acc[4][2];
    __builtin_amdgcn_s_setprio(1);
    #pragma unroll
    for (int kk = 0; kk < 4; ++kk) {
      half8 bh[2], bl[2];
      #pragma unroll
      for (int nf = 0; nf < 2; ++nf) {
        bh[nf] = *(const half8*)(smem + bcur + kk * 2048 + nf * 1024 + lane * 16);
        bl[nf] = *(const half8*)(smem + bcur + 8192 + kk * 2048 + nf * 1024 + lane * 16);
      }
      // term hh (C-init with sj at kk==0)
      #pragma unroll
      for (int mf = 0; mf < 4; ++mf)
        #pragma unroll
        for (int nf = 0; nf < 2; ++nf) {
          if (kk == 0) {
            float sj = nf ? sjc1 : sjc0;
            f32x4 c0 = {sj, sj, sj, sj};
            acc[mf][nf] = __builtin_amdgcn_mfma_f32_16x16x32_f16(ah[mf][0], bh[nf], c0, 0, 0, 0);
          } else {
            acc[mf][nf] = __builtin_amdgcn_mfma_f32_16x16x32_f16(ah[mf][kk], bh[nf], acc[mf][nf], 0, 0, 0);
          }
        }
      // term hl
      #pragma unroll
      for (int mf = 0; mf < 4; ++mf)
        #pragma unroll
        for (int nf = 0; nf < 2; ++nf)
          acc[mf][nf] = __builtin_amdgcn_mfma_f32_16x16x32_f16(ah[mf][kk], bl[nf], acc[mf][nf], 0, 0, 0);
      // term lh
      #pragma unroll
      for (int mf = 0; mf < 4; ++mf)
        #pragma unroll
        for (int nf = 0; nf < 2; ++nf)
          acc[mf][nf] = __builtin_amdgcn_mfma_f32_16x16x32_f16(al[mf][kk], bh[nf], acc[mf][nf], 0, 0, 0);
    }
    __builtin_amdgcn_s_setprio(0);

    // ---- top-2 fold (fmed3, 4 VALU/elem); acc[r] = sqb[j] - 2*dot already ----
    // C/D layout: col = lane&15, row = (lane>>4)*4 + reg
    #pragma unroll
    for (int nf = 0; nf < 2; ++nf) {
      int colg = colg0 + it * BN_ + nf * 16;
      #pragma unroll
      for (int mf = 0; mf < 4; ++mf)
        #pragma unroll
        for (int r = 0; r < 4; ++r) {
          int s = mf * 4 + r;
          float t = acc[mf][nf][r];
          best1[s] = __builtin_amdgcn_fmed3f(t, best0[s], best1[s]);
          bool lt0 = t < best0[s];
          best0[s] = fminf(t, best0[s]);
          bj[s]    = lt0 ? colg : bj[s];
        }
    }

    // ---- counted drain: only tile t+1's 4 per-wave loads; t+2's stay in flight ----
    if (it + 2 < niter) asm volatile("s_waitcnt vmcnt(4)" ::: "memory");
    else                asm volatile("s_waitcnt vmcnt(0)" ::: "memory");
    __builtin_amdgcn_s_barrier();
    asm volatile("" ::: "memory");

    sjc0 = sjn0; sjc1 = sjn1;
    bcur   = (bcur   == 32768) ? 0 : bcur   + 16384;
    bstage = (bstage == 32768) ? 0 : bstage + 16384;
  }

  // ---- merge across the 16 col-lanes (same g), index tie-break ----
  #pragma unroll
  for (int off = 1; off < 16; off <<= 1) {
    #pragma unroll
    for (int s = 0; s < 16; ++s) {
      float e0 = __shfl_xor(best0[s], off, 64);
      float e1 = __shfl_xor(best1[s], off, 64);
      int   f0 = __shfl_xor(bj[s],    off, 64);
      if (e0 < best0[s] || (e0 == best0[s] && f0 < bj[s])) {
        best1[s] = fminf(best0[s], e1);
        best0[s] = e0;
        bj[s]    = f0;
      } else {
        best1[s] = fminf(best1[s], e0);
      }
    }
  }

  if (l15 == 0) {
    #pragma unroll
    for (int s = 0; s < 16; ++s) {
      int mf = s >> 2, r = s & 3;
      int row = i0 + wid * 64 + mf * 16 + g * 4 + r;
      p_d0[row * PARTS_ + cspl] = best0[s];
      p_d1[row * PARTS_ + cspl] = best1[s];
      p_j0[row * PARTS_ + cspl] = bj[s];
    }
  }
}

__global__ void nn_final(const float* __restrict__ sqa,
                         const float* __restrict__ p_d0,
                         const float* __restrict__ p_d1,
                         const int* __restrict__ p_j0,
                         float* __restrict__ out, int B) {
  int row = blockIdx.x * blockDim.x + threadIdx.x;
  if (row >= B) return;
  float d0 = FLT_MAX, d1 = FLT_MAX;
  int j0 = 0x7fffffff;
  for (int cs = 0; cs < PARTS_; ++cs) {
    float e0 = p_d0[row * PARTS_ + cs];
    float e1 = p_d1[row * PARTS_ + cs];
    int   f0 = p_j0[row * PARTS_ + cs];
    if (e0 < d0 || (e0 == d0 && f0 < j0)) {
      d1 = fminf(d0, e1);
      d0 = e0;
      j0 = f0;
    } else {
      d1 = fminf(d1, e0);
    }
  }
  float sa = sqa[row];
  float v0 = sqrtf(fmaxf(sa + d0, 0.f));
  float v1 = sqrtf(fmaxf(sa + d1, 0.f));
  float ratio = v0 / v1;
  bool m = (ratio <= 0.8f);
  out[row]             = m ? ratio : 0.f;
  out[B + row * 2]     = (float)row;
  out[B + row * 2 + 1] = (float)j0;
  out[3 * B + row]     = m ? 1.f : 0.f;
}

extern "C" void kernel_launch(void* const* d_in, const int* in_sizes, int n_in,
                              void* d_out, int out_size, void* d_ws, size_t ws_size,
                              hipStream_t stream) {
  const float* d1 = (const float*)d_in[0];
  const float* d2 = (const float*)d_in[1];
  const int B = in_sizes[0] / D_;    // 16384

  float* ws   = (float*)d_ws;
  float* sqa  = ws;                       // [0, B)
  float* sqb  = ws + B;                   // [B, 2B)
  float* p_d0 = ws + 2 * B;               // [2B, 10B)
  float* p_d1 = ws + 10 * B;              // [10B, 18B)
  int*   p_j0 = (int*)(ws + 18 * B);      // [18B, 26B)
  _Float16* Ahi  = (_Float16*)(ws + 26 * B);
  _Float16* Alo  = Ahi + (size_t)B * D_;
  _Float16* BhiP = Alo + (size_t)B * D_;
  _Float16* BloP = BhiP + (size_t)B * D_;

  // fused convert + norms (A row-major; B fragment-packed, scaled by -2; sq norms)
  int ngroups = 2 * B * 16;
  convert_kernel<<<(ngroups + 255) / 256, 256, 0, stream>>>(d1, d2, Ahi, Alo, BhiP, BloP, sqa, B);

  // main MFMA kernel: 56 KiB dynamic LDS (3 bufs + sq strip), 2 blocks/CU
  hipFuncSetAttribute((const void*)nn_mfma,
                      hipFuncAttributeMaxDynamicSharedMemorySize, 57344);
  nn_mfma<<<(B / BM_) * CS_, 256, 57344, stream>>>(Ahi, Alo, BhiP, BloP, sqb,
                                                   p_d0, p_d1, p_j0, B);

  // final merge + outputs
  nn_final<<<(B + 255) / 256, 256, 0, stream>>>(sqa, p_d0, p_d1, p_j0, (float*)d_out, B);
}